// Round 1
// baseline (1248.092 us; speedup 1.0000x reference)
//
#include <hip/hip_runtime.h>
#include <cmath>

#define TILE_M 64
#define TILE_N 64
#define TILE_K 16

// ---------------------------------------------------------------------------
// K1: h1 = relu(F @ Wg1 + b1), fp64 accumulate, fp64 output to workspace.
// F: [M,1024] fp32, Wg1: [1024,256] fp32 row-major, out: [M,256] double.
// ---------------------------------------------------------------------------
__global__ __launch_bounds__(256) void gemm1_relu_f64(
    const float* __restrict__ A,
    const float* __restrict__ W,
    const float* __restrict__ bias,
    double* __restrict__ out,
    int M)
{
    const int K = 1024, N = 256;
    __shared__ float As[TILE_K][TILE_M + 4];
    __shared__ float Bs[TILE_K][TILE_N];

    const int tid = threadIdx.x;
    const int bm = blockIdx.x * TILE_M;
    const int bn = blockIdx.y * TILE_N;

    const int lak = tid & 15, lam = tid >> 4;   // A loader: k, m-base
    const int lbn = tid & 63, lbk = tid >> 6;   // B loader: n, k-base
    const int tx = tid & 15, ty = tid >> 4;     // micro-tile coords

    double acc[4][4];
    #pragma unroll
    for (int i = 0; i < 4; ++i)
        #pragma unroll
        for (int j = 0; j < 4; ++j) acc[i][j] = 0.0;

    for (int k0 = 0; k0 < K; k0 += TILE_K) {
        #pragma unroll
        for (int i = 0; i < 4; ++i) {
            int m = lam + 16 * i;
            As[lak][m] = A[(size_t)(bm + m) * K + (k0 + lak)];
        }
        #pragma unroll
        for (int i = 0; i < 4; ++i) {
            int kk = lbk + 4 * i;
            Bs[kk][lbn] = W[(size_t)(k0 + kk) * N + (bn + lbn)];
        }
        __syncthreads();
        #pragma unroll
        for (int k = 0; k < TILE_K; ++k) {
            double da[4], db[4];
            #pragma unroll
            for (int i = 0; i < 4; ++i) da[i] = (double)As[k][ty * 4 + i];
            #pragma unroll
            for (int j = 0; j < 4; ++j) db[j] = (double)Bs[k][tx * 4 + j];
            #pragma unroll
            for (int i = 0; i < 4; ++i)
                #pragma unroll
                for (int j = 0; j < 4; ++j)
                    acc[i][j] += da[i] * db[j];
        }
        __syncthreads();
    }

    #pragma unroll
    for (int i = 0; i < 4; ++i) {
        int row = bm + ty * 4 + i;
        #pragma unroll
        for (int j = 0; j < 4; ++j) {
            int col = bn + tx * 4 + j;
            double z = acc[i][j] + (double)bias[col];
            out[(size_t)row * N + col] = (z > 0.0) ? z : 0.0;
        }
    }
}

// ---------------------------------------------------------------------------
// K2: z2 = h1 @ Wg2 + b2; gw = sigmoid(z2); gated = F*gw;
//     comp = (gated > 0.3) ? 0 : gated   (decision taken in fp64!)
// h1: [M,256] double, Wg2: [256,1024] fp32, out comp: [M,1024] fp32 (d_out).
// ---------------------------------------------------------------------------
__global__ __launch_bounds__(256) void gemm2_comp_f64(
    const double* __restrict__ A,
    const float* __restrict__ W,
    const float* __restrict__ bias,
    const float* __restrict__ F,
    float* __restrict__ out,
    int M)
{
    const int K = 256, N = 1024;
    __shared__ double As[TILE_K][TILE_M + 2];
    __shared__ float  Bs[TILE_K][TILE_N];

    const int tid = threadIdx.x;
    const int bm = blockIdx.x * TILE_M;
    const int bn = blockIdx.y * TILE_N;

    const int lak = tid & 15, lam = tid >> 4;
    const int lbn = tid & 63, lbk = tid >> 6;
    const int tx = tid & 15, ty = tid >> 4;

    double acc[4][4];
    #pragma unroll
    for (int i = 0; i < 4; ++i)
        #pragma unroll
        for (int j = 0; j < 4; ++j) acc[i][j] = 0.0;

    for (int k0 = 0; k0 < K; k0 += TILE_K) {
        #pragma unroll
        for (int i = 0; i < 4; ++i) {
            int m = lam + 16 * i;
            As[lak][m] = A[(size_t)(bm + m) * K + (k0 + lak)];
        }
        #pragma unroll
        for (int i = 0; i < 4; ++i) {
            int kk = lbk + 4 * i;
            Bs[kk][lbn] = W[(size_t)(k0 + kk) * N + (bn + lbn)];
        }
        __syncthreads();
        #pragma unroll
        for (int k = 0; k < TILE_K; ++k) {
            double da[4], db[4];
            #pragma unroll
            for (int i = 0; i < 4; ++i) da[i] = As[k][ty * 4 + i];
            #pragma unroll
            for (int j = 0; j < 4; ++j) db[j] = (double)Bs[k][tx * 4 + j];
            #pragma unroll
            for (int i = 0; i < 4; ++i)
                #pragma unroll
                for (int j = 0; j < 4; ++j)
                    acc[i][j] += da[i] * db[j];
        }
        __syncthreads();
    }

    #pragma unroll
    for (int i = 0; i < 4; ++i) {
        int row = bm + ty * 4 + i;
        #pragma unroll
        for (int j = 0; j < 4; ++j) {
            int col = bn + tx * 4 + j;
            double z = acc[i][j] + (double)bias[col];
            double gw = 1.0 / (1.0 + exp(-z));
            double g = (double)F[(size_t)row * N + col] * gw;
            double c = (g > 0.3) ? 0.0 : g;
            out[(size_t)row * N + col] = (float)c;
        }
    }
}

// ---------------------------------------------------------------------------
// K3: per-row finalize (in-place on d_out).
// cur_sp -> rw MLP -> dyn -> mean/std(ddof=1)/max -> thr MLP -> mask.
// ---------------------------------------------------------------------------
__device__ __forceinline__ double block_reduce(double v, double* sm, int tid, int op)
{
    // op: 0 = sum, 1 = max. 256 threads = 4 waves of 64.
    #pragma unroll
    for (int o = 32; o > 0; o >>= 1) {
        double other = __shfl_down(v, o, 64);
        v = op ? fmax(v, other) : (v + other);
    }
    if ((tid & 63) == 0) sm[tid >> 6] = v;
    __syncthreads();
    if (tid == 0) {
        double r = sm[0];
        for (int w = 1; w < 4; ++w) r = op ? fmax(r, sm[w]) : (r + sm[w]);
        sm[4] = r;
    }
    __syncthreads();
    double r = sm[4];
    __syncthreads();   // safe to reuse sm afterwards
    return r;
}

__global__ __launch_bounds__(256) void finalize_rows(
    float* __restrict__ C,              // [M,1024] in: comp, out: result
    const float* __restrict__ wr1, const float* __restrict__ br1,
    const float* __restrict__ wr2, const float* __restrict__ br2,
    const float* __restrict__ wm1, const float* __restrict__ bm1,
    const float* __restrict__ wm2, const float* __restrict__ bm2)
{
    const int D = 1024;
    const int tid = threadIdx.x;
    const size_t base = (size_t)blockIdx.x * D;
    __shared__ double sm[8];

    float4 c4 = *(const float4*)(C + base + tid * 4);
    double c[4] = {(double)c4.x, (double)c4.y, (double)c4.z, (double)c4.w};

    // ---- current sparsity: mean(|comp| < 0.1) ----
    double cnt = 0.0;
    #pragma unroll
    for (int i = 0; i < 4; ++i) cnt += (fabs(c[i]) < 0.1) ? 1.0 : 0.0;
    cnt = block_reduce(cnt, sm, tid, 0);
    double cur_sp = cnt / 1024.0;

    // ---- rw = sigmoid(relu([cur_sp, 0.1] @ Wr1 + br1) @ Wr2 + br2) ----
    double hid[16];
    #pragma unroll
    for (int h = 0; h < 16; ++h) {
        double z = cur_sp * (double)wr1[h] + 0.1 * (double)wr1[16 + h] + (double)br1[h];
        hid[h] = (z > 0.0) ? z : 0.0;
    }
    const int col0 = tid * 4;
    double z[4];
    #pragma unroll
    for (int j = 0; j < 4; ++j) z[j] = (double)br2[col0 + j];
    #pragma unroll
    for (int h = 0; h < 16; ++h) {
        float4 w4 = *(const float4*)(wr2 + (size_t)h * D + col0);
        z[0] += hid[h] * (double)w4.x;
        z[1] += hid[h] * (double)w4.y;
        z[2] += hid[h] * (double)w4.z;
        z[3] += hid[h] * (double)w4.w;
    }
    double dyn[4];
    #pragma unroll
    for (int j = 0; j < 4; ++j) {
        double rw = 1.0 / (1.0 + exp(-z[j]));
        dyn[j] = c[j] * rw;
    }

    // ---- row stats: mean, std (ddof=1), max ----
    double s = dyn[0] + dyn[1] + dyn[2] + dyn[3];
    s = block_reduce(s, sm, tid, 0);
    double mean = s / 1024.0;

    double sq = 0.0;
    #pragma unroll
    for (int j = 0; j < 4; ++j) { double d = dyn[j] - mean; sq += d * d; }
    sq = block_reduce(sq, sm, tid, 0);
    double sd = sqrt(sq / 1023.0);

    double mx = fmax(fmax(dyn[0], dyn[1]), fmax(dyn[2], dyn[3]));
    mx = block_reduce(mx, sm, tid, 1);

    // ---- thr = sigmoid(relu([mean, sd, mx] @ Wm1 + bm1) @ Wm2 + bm2) ----
    double acc2 = (double)bm2[0];
    #pragma unroll
    for (int h = 0; h < 16; ++h) {
        double hz = mean * (double)wm1[h] + sd * (double)wm1[16 + h]
                  + mx * (double)wm1[32 + h] + (double)bm1[h];
        hz = (hz > 0.0) ? hz : 0.0;
        acc2 += hz * (double)wm2[h];
    }
    double thr = 1.0 / (1.0 + exp(-acc2));

    // ---- final mask: dyn * (|dyn| > thr) ----
    float4 o4;
    o4.x = (float)((fabs(dyn[0]) > thr) ? dyn[0] : 0.0);
    o4.y = (float)((fabs(dyn[1]) > thr) ? dyn[1] : 0.0);
    o4.z = (float)((fabs(dyn[2]) > thr) ? dyn[2] : 0.0);
    o4.w = (float)((fabs(dyn[3]) > thr) ? dyn[3] : 0.0);
    *(float4*)(C + base + tid * 4) = o4;
}

// ---------------------------------------------------------------------------
extern "C" void kernel_launch(void* const* d_in, const int* in_sizes, int n_in,
                              void* d_out, int out_size, void* d_ws, size_t ws_size,
                              hipStream_t stream)
{
    const float* F   = (const float*)d_in[0];
    const float* wg1 = (const float*)d_in[1];
    const float* bg1 = (const float*)d_in[2];
    const float* wg2 = (const float*)d_in[3];
    const float* bg2 = (const float*)d_in[4];
    // d_in[5..8] = competition calculator weights: provably dead code (win == False always)
    const float* wr1 = (const float*)d_in[9];
    const float* br1 = (const float*)d_in[10];
    const float* wr2 = (const float*)d_in[11];
    const float* br2 = (const float*)d_in[12];
    const float* wm1 = (const float*)d_in[13];
    const float* bm1 = (const float*)d_in[14];
    const float* wm2 = (const float*)d_in[15];
    const float* bm2 = (const float*)d_in[16];

    float* out = (float*)d_out;
    const int M = in_sizes[0] / 1024;      // 32768
    double* H1 = (double*)d_ws;            // [M, 256] doubles = 64 MiB

    gemm1_relu_f64<<<dim3(M / TILE_M, 256 / TILE_N), 256, 0, stream>>>(F, wg1, bg1, H1, M);
    gemm2_comp_f64<<<dim3(M / TILE_M, 1024 / TILE_N), 256, 0, stream>>>(H1, wg2, bg2, F, out, M);
    finalize_rows<<<M, 256, 0, stream>>>(out, wr1, br1, wr2, br2, wm1, bm1, wm2, bm2);
}

// Round 2
// 1030.362 us; speedup vs baseline: 1.2113x; 1.2113x over previous
//
#include <hip/hip_runtime.h>
#include <cmath>

#define TM 128
#define TN 128
#define TK 16
#define LDSW 132          // padded LDS row width (floats)
#define BAND 1e-4
#define FIXCAP 262144u

// ---------------------------------------------------------------------------
// Shared 128x128x16 fp32 tile mainloop, 256 threads, 8x8 micro-tile split as
// 2x2 blocks of 4x4 (so LDS reads are 16B with <=2-way bank aliasing).
// ---------------------------------------------------------------------------
#define GEMM_MAINLOOP(Aptr, Wptr, Kdim, Ndim)                                   \
    __shared__ float As[TK][LDSW];                                              \
    __shared__ float Bs[TK][LDSW];                                              \
    const int tid = threadIdx.x;                                                \
    const int bm = blockIdx.x * TM;                                             \
    const int bn = blockIdx.y * TN;                                             \
    const int tx = tid & 15, ty = tid >> 4;                                     \
    const int ar = tid >> 2, aq = tid & 3;                                      \
    const int bk = tid >> 5, bn4 = (tid & 31) * 4;                              \
    float acc[2][2][4][4];                                                      \
    _Pragma("unroll") for (int a = 0; a < 2; ++a)                               \
    _Pragma("unroll") for (int b = 0; b < 2; ++b)                               \
    _Pragma("unroll") for (int i = 0; i < 4; ++i)                               \
    _Pragma("unroll") for (int j = 0; j < 4; ++j) acc[a][b][i][j] = 0.f;        \
    for (int k0 = 0; k0 < (Kdim); k0 += TK) {                                   \
        float4 a0 = *(const float4*)((Aptr) + (size_t)(bm + ar) * (Kdim) + k0 + aq * 4);       \
        float4 a1 = *(const float4*)((Aptr) + (size_t)(bm + ar + 64) * (Kdim) + k0 + aq * 4);  \
        float4 b0 = *(const float4*)((Wptr) + (size_t)(k0 + bk) * (Ndim) + bn + bn4);          \
        float4 b1 = *(const float4*)((Wptr) + (size_t)(k0 + bk + 8) * (Ndim) + bn + bn4);      \
        __syncthreads();                                                        \
        As[aq * 4 + 0][ar] = a0.x; As[aq * 4 + 1][ar] = a0.y;                   \
        As[aq * 4 + 2][ar] = a0.z; As[aq * 4 + 3][ar] = a0.w;                   \
        As[aq * 4 + 0][ar + 64] = a1.x; As[aq * 4 + 1][ar + 64] = a1.y;         \
        As[aq * 4 + 2][ar + 64] = a1.z; As[aq * 4 + 3][ar + 64] = a1.w;         \
        *(float4*)&Bs[bk][bn4] = b0;                                            \
        *(float4*)&Bs[bk + 8][bn4] = b1;                                        \
        __syncthreads();                                                        \
        _Pragma("unroll") for (int k = 0; k < TK; ++k) {                        \
            float4 da0 = *(const float4*)&As[k][ty * 4];                        \
            float4 da1 = *(const float4*)&As[k][64 + ty * 4];                   \
            float4 db0 = *(const float4*)&Bs[k][tx * 4];                        \
            float4 db1 = *(const float4*)&Bs[k][64 + tx * 4];                   \
            const float* dap[2] = {&da0.x, &da1.x};                             \
            const float* dbp[2] = {&db0.x, &db1.x};                             \
            _Pragma("unroll") for (int a = 0; a < 2; ++a)                       \
            _Pragma("unroll") for (int b = 0; b < 2; ++b)                       \
            _Pragma("unroll") for (int i = 0; i < 4; ++i)                       \
            _Pragma("unroll") for (int j = 0; j < 4; ++j)                       \
                acc[a][b][i][j] = fmaf(dap[a][i], dbp[b][j], acc[a][b][i][j]);  \
        }                                                                       \
    }

// ---------------------------------------------------------------------------
// K1: h1 = relu(F @ Wg1 + b1), fp32.  F:[M,1024], Wg1:[1024,256], out:[M,256]
// ---------------------------------------------------------------------------
__global__ __launch_bounds__(256) void gemm1_f32(
    const float* __restrict__ A, const float* __restrict__ W,
    const float* __restrict__ bias, float* __restrict__ out, int M)
{
    const int K = 1024, N = 256;
    GEMM_MAINLOOP(A, W, K, N)
    #pragma unroll
    for (int a = 0; a < 2; ++a) {
        #pragma unroll
        for (int b = 0; b < 2; ++b) {
            const int col = bn + b * 64 + tx * 4;
            float4 bi = *(const float4*)(bias + col);
            #pragma unroll
            for (int i = 0; i < 4; ++i) {
                const int row = bm + a * 64 + ty * 4 + i;
                float4 o;
                o.x = fmaxf(acc[a][b][i][0] + bi.x, 0.f);
                o.y = fmaxf(acc[a][b][i][1] + bi.y, 0.f);
                o.z = fmaxf(acc[a][b][i][2] + bi.z, 0.f);
                o.w = fmaxf(acc[a][b][i][3] + bi.w, 0.f);
                *(float4*)(out + (size_t)row * N + col) = o;
            }
        }
    }
}

// ---------------------------------------------------------------------------
// K2: z2 = h1 @ Wg2 + b2; g = F * sigmoid(z2); comp = (g>0.3)?0:g.
// Flags |g-0.3| < BAND for exact fp64 fixup.  out = comp (fp32, d_out).
// ---------------------------------------------------------------------------
__global__ __launch_bounds__(256) void gemm2_f32(
    const float* __restrict__ A, const float* __restrict__ W,
    const float* __restrict__ bias, const float* __restrict__ F,
    float* __restrict__ out, unsigned* __restrict__ counter,
    uint2* __restrict__ list, int M)
{
    const int K = 256, N = 1024;
    GEMM_MAINLOOP(A, W, K, N)
    #pragma unroll
    for (int a = 0; a < 2; ++a) {
        #pragma unroll
        for (int b = 0; b < 2; ++b) {
            const int col = bn + b * 64 + tx * 4;
            float4 bi = *(const float4*)(bias + col);
            const float* bip = &bi.x;
            #pragma unroll
            for (int i = 0; i < 4; ++i) {
                const int row = bm + a * 64 + ty * 4 + i;
                float4 fv = *(const float4*)(F + (size_t)row * N + col);
                const float* fvp = &fv.x;
                float4 o;
                float* op = &o.x;
                #pragma unroll
                for (int j = 0; j < 4; ++j) {
                    double z = (double)acc[a][b][i][j] + (double)bip[j];
                    double gw = 1.0 / (1.0 + exp(-z));
                    double g = (double)fvp[j] * gw;
                    if (fabs(g - 0.3) < BAND) {
                        unsigned idx = atomicAdd(counter, 1u);
                        if (idx < FIXCAP) list[idx] = make_uint2((unsigned)row, (unsigned)(col + j));
                    }
                    double c = (g > 0.3) ? 0.0 : g;
                    op[j] = (float)c;
                }
                *(float4*)(out + (size_t)row * N + col) = o;
            }
        }
    }
}

// ---------------------------------------------------------------------------
// fix1: exact fp64 recompute of comp for flagged (row,col) elements.
// One block per list entry (strided).  256 threads: thread t computes
// h1[t] = relu(F[row,:] . Wg1[:,t] + b1[t]) in fp64, then block-reduces
// h1[t]*Wg2[t,col] to get exact z2.
// ---------------------------------------------------------------------------
__global__ __launch_bounds__(256) void fix_exact(
    const float* __restrict__ F, const float* __restrict__ Wg1,
    const float* __restrict__ bg1, const float* __restrict__ Wg2,
    const float* __restrict__ bg2, const unsigned* __restrict__ counter,
    const uint2* __restrict__ list, float* __restrict__ out)
{
    __shared__ float Fs[1024];
    __shared__ double red[4];
    const int tid = threadIdx.x;
    unsigned cnt = *counter;
    if (cnt > FIXCAP) cnt = FIXCAP;

    for (unsigned e = blockIdx.x; e < cnt; e += gridDim.x) {
        const unsigned row = list[e].x, col = list[e].y;
        // stage F row
        *(float4*)&Fs[tid * 4] = *(const float4*)(F + (size_t)row * 1024 + tid * 4);
        __syncthreads();
        double acc = 0.0;
        #pragma unroll 4
        for (int j = 0; j < 1024; ++j)
            acc += (double)Fs[j] * (double)Wg1[(size_t)j * 256 + tid];
        double h = acc + (double)bg1[tid];
        h = (h > 0.0) ? h : 0.0;
        double p = h * (double)Wg2[(size_t)tid * 1024 + col];
        // block reduce sum(p)
        #pragma unroll
        for (int o = 32; o > 0; o >>= 1) p += __shfl_down(p, o, 64);
        if ((tid & 63) == 0) red[tid >> 6] = p;
        __syncthreads();
        if (tid == 0) {
            double z2 = red[0] + red[1] + red[2] + red[3] + (double)bg2[col];
            double gw = 1.0 / (1.0 + exp(-z2));
            double g = (double)Fs[col] * gw;
            double c = (g > 0.3) ? 0.0 : g;
            out[(size_t)row * 1024 + col] = (float)c;
        }
        __syncthreads();
    }
}

// ---------------------------------------------------------------------------
// K3: per-row finalize (in-place on d_out) — unchanged from round 1.
// ---------------------------------------------------------------------------
__device__ __forceinline__ double block_reduce(double v, double* sm, int tid, int op)
{
    #pragma unroll
    for (int o = 32; o > 0; o >>= 1) {
        double other = __shfl_down(v, o, 64);
        v = op ? fmax(v, other) : (v + other);
    }
    if ((tid & 63) == 0) sm[tid >> 6] = v;
    __syncthreads();
    if (tid == 0) {
        double r = sm[0];
        for (int w = 1; w < 4; ++w) r = op ? fmax(r, sm[w]) : (r + sm[w]);
        sm[4] = r;
    }
    __syncthreads();
    double r = sm[4];
    __syncthreads();
    return r;
}

__global__ __launch_bounds__(256) void finalize_rows(
    float* __restrict__ C,
    const float* __restrict__ wr1, const float* __restrict__ br1,
    const float* __restrict__ wr2, const float* __restrict__ br2,
    const float* __restrict__ wm1, const float* __restrict__ bm1,
    const float* __restrict__ wm2, const float* __restrict__ bm2)
{
    const int D = 1024;
    const int tid = threadIdx.x;
    const size_t base = (size_t)blockIdx.x * D;
    __shared__ double sm[8];

    float4 c4 = *(const float4*)(C + base + tid * 4);
    double c[4] = {(double)c4.x, (double)c4.y, (double)c4.z, (double)c4.w};

    double cnt = 0.0;
    #pragma unroll
    for (int i = 0; i < 4; ++i) cnt += (fabs(c[i]) < 0.1) ? 1.0 : 0.0;
    cnt = block_reduce(cnt, sm, tid, 0);
    double cur_sp = cnt / 1024.0;

    double hid[16];
    #pragma unroll
    for (int h = 0; h < 16; ++h) {
        double z = cur_sp * (double)wr1[h] + 0.1 * (double)wr1[16 + h] + (double)br1[h];
        hid[h] = (z > 0.0) ? z : 0.0;
    }
    const int col0 = tid * 4;
    double z[4];
    #pragma unroll
    for (int j = 0; j < 4; ++j) z[j] = (double)br2[col0 + j];
    #pragma unroll
    for (int h = 0; h < 16; ++h) {
        float4 w4 = *(const float4*)(wr2 + (size_t)h * D + col0);
        z[0] += hid[h] * (double)w4.x;
        z[1] += hid[h] * (double)w4.y;
        z[2] += hid[h] * (double)w4.z;
        z[3] += hid[h] * (double)w4.w;
    }
    double dyn[4];
    #pragma unroll
    for (int j = 0; j < 4; ++j) {
        double rw = 1.0 / (1.0 + exp(-z[j]));
        dyn[j] = c[j] * rw;
    }

    double s = dyn[0] + dyn[1] + dyn[2] + dyn[3];
    s = block_reduce(s, sm, tid, 0);
    double mean = s / 1024.0;

    double sq = 0.0;
    #pragma unroll
    for (int j = 0; j < 4; ++j) { double d = dyn[j] - mean; sq += d * d; }
    sq = block_reduce(sq, sm, tid, 0);
    double sd = sqrt(sq / 1023.0);

    double mx = fmax(fmax(dyn[0], dyn[1]), fmax(dyn[2], dyn[3]));
    mx = block_reduce(mx, sm, tid, 1);

    double acc2 = (double)bm2[0];
    #pragma unroll
    for (int h = 0; h < 16; ++h) {
        double hz = mean * (double)wm1[h] + sd * (double)wm1[16 + h]
                  + mx * (double)wm1[32 + h] + (double)bm1[h];
        hz = (hz > 0.0) ? hz : 0.0;
        acc2 += hz * (double)wm2[h];
    }
    double thr = 1.0 / (1.0 + exp(-acc2));

    float4 o4;
    o4.x = (float)((fabs(dyn[0]) > thr) ? dyn[0] : 0.0);
    o4.y = (float)((fabs(dyn[1]) > thr) ? dyn[1] : 0.0);
    o4.z = (float)((fabs(dyn[2]) > thr) ? dyn[2] : 0.0);
    o4.w = (float)((fabs(dyn[3]) > thr) ? dyn[3] : 0.0);
    *(float4*)(C + base + tid * 4) = o4;
}

// ---------------------------------------------------------------------------
extern "C" void kernel_launch(void* const* d_in, const int* in_sizes, int n_in,
                              void* d_out, int out_size, void* d_ws, size_t ws_size,
                              hipStream_t stream)
{
    const float* F   = (const float*)d_in[0];
    const float* wg1 = (const float*)d_in[1];
    const float* bg1 = (const float*)d_in[2];
    const float* wg2 = (const float*)d_in[3];
    const float* bg2 = (const float*)d_in[4];
    // d_in[5..8]: competition calculator — provably dead (win == False always)
    const float* wr1 = (const float*)d_in[9];
    const float* br1 = (const float*)d_in[10];
    const float* wr2 = (const float*)d_in[11];
    const float* br2 = (const float*)d_in[12];
    const float* wm1 = (const float*)d_in[13];
    const float* bm1 = (const float*)d_in[14];
    const float* wm2 = (const float*)d_in[15];
    const float* bm2 = (const float*)d_in[16];

    float* out = (float*)d_out;
    const int M = in_sizes[0] / 1024;                      // 32768

    float*    h1      = (float*)d_ws;                      // 32 MiB
    uint2*    list    = (uint2*)((char*)d_ws + (32u << 20));   // 2 MiB
    unsigned* counter = (unsigned*)((char*)d_ws + (34u << 20));

    hipMemsetAsync(counter, 0, sizeof(unsigned), stream);
    gemm1_f32<<<dim3(M / TM, 256 / TN), 256, 0, stream>>>(F, wg1, bg1, h1, M);
    gemm2_f32<<<dim3(M / TM, 1024 / TN), 256, 0, stream>>>(h1, wg2, bg2, F, out, counter, list, M);
    fix_exact<<<2048, 256, 0, stream>>>(F, wg1, bg1, wg2, bg2, counter, list, out);
    finalize_rows<<<M, 256, 0, stream>>>(out, wr1, br1, wr2, br2, wm1, bm1, wm2, bm2);
}